// Round 7
// baseline (6504.361 us; speedup 1.0000x reference)
//
#include <hip/hip_runtime.h>
#include <hip/hip_fp16.h>
#include <cstddef>
#include <cstdint>

#define U_DIM 256
#define G_DIM 1024          // 4*U
#define T_DIM 512
#define B_DIM 64
#define TC    128           // timesteps per chunk
#define NCHUNK (T_DIM / TC)

#define NGRP      4         // batch-row groups (16 rows each)
#define NSLICE    16        // blocks per group (16 hidden units each)

typedef _Float16 f16x8 __attribute__((ext_vector_type(8)));
typedef float    f32x4 __attribute__((ext_vector_type(4)));

__device__ __forceinline__ float fsig(float x) {
    return 1.0f / (1.0f + __expf(-x));
}
__device__ __forceinline__ float ftanh(float x) {
    return 2.0f * fsig(2.0f * x) - 1.0f;
}

// ---------------------------------------------------------------------------
// Pack U [256,1024] fp32 -> P: [32 groups][1024 cols] of uint4.
// P[g][n] = f16 of U[8g+0..8g+7][n], packed 2-per-u32 (k ascending).
// This is exactly the MFMA B-fragment granularity: lane needs 8 consecutive k.
// ---------------------------------------------------------------------------
__global__ __launch_bounds__(256)
void pack_w(const float* __restrict__ U, uint4* __restrict__ P)
{
    const int idx = blockIdx.x * 256 + threadIdx.x;   // 0..32767
    const int g = idx >> 10;
    const int n = idx & 1023;
    uint vals[4];
    #pragma unroll
    for (int j = 0; j < 4; ++j) {
        const int k = g * 8 + j * 2;
        const __half a = __float2half_rn(U[(size_t)k * G_DIM + n]);
        const __half b = __float2half_rn(U[(size_t)(k + 1) * G_DIM + n]);
        const unsigned short ua = __builtin_bit_cast(unsigned short, a);
        const unsigned short ub = __builtin_bit_cast(unsigned short, b);
        vals[j] = (uint)ua | ((uint)ub << 16);
    }
    P[idx] = make_uint4(vals[0], vals[1], vals[2], vals[3]);
}

// ---------------------------------------------------------------------------
// Cooperative recurrent kernel. Grid = 64 blocks x 256 threads.
// Block bid -> group g=(bid&7)>>1 (rows [16g,16g+16)), slice s (units [16s,16s+16)).
// The 16 blocks of a group land on XCD pair {2g,2g+1} under %8 round-robin
// (perf heuristic only; correctness uses agent-scope atomics).
// Wave w (=tid>>6) owns gate w. Per step:
//   Z[16 rows][64 cols] = XZ_t + H[16,256] @ U_slice[256,64]  via 16x16x32 f16 MFMA
// B-frags (U slice) are loaded ONCE into 32 VGPRs/lane. H arrives per step
// from the group's global exchange buffer (flag barrier), staged in LDS.
// Thread tid then owns (row=tid>>4, unit=tid&15): c in register, h published.
// ---------------------------------------------------------------------------
__global__ __launch_bounds__(256)
void lstm_mfma(const float* __restrict__ xz, const uint4* __restrict__ P,
               const float* __restrict__ res, float* __restrict__ outseq,
               float* __restrict__ hstate, float* __restrict__ cstate,
               __half* __restrict__ Hx, unsigned* __restrict__ flags,
               int t0, int firstchunk)
{
    const int bid = blockIdx.x;
    const int g = (bid & 7) >> 1;
    const int s = (bid & 1) | ((bid >> 3) << 1);
    const int tid = threadIdx.x;
    const int w = tid >> 6;        // wave = gate index
    const int l = tid & 63;

    __shared__ __align__(16) __half Hlds[16 * 256];   // 8 KB, XOR-swizzled
    __shared__ float zg[4][16][16];                   // 4 KB activated gates

    // ---- B fragments: U slice resident in registers (32 VGPRs) ----
    uint4 bf[8];
    {
        const int coln = 256 * w + 16 * s + (l & 15);
        #pragma unroll
        for (int kt = 0; kt < 8; ++kt)
            bf[kt] = P[(size_t)(4 * kt + (l >> 4)) * G_DIM + coln];
    }

    const int row = tid >> 4;      // group-local batch row (epilogue mapping)
    const int un  = tid & 15;      // block-local unit
    const int bg  = 16 * g + row;  // global batch row
    const int ug  = 16 * s + un;   // global unit

    __half* __restrict__ Hgrp = Hx + (size_t)g * 2 * 4096;   // [2][16][256]
    unsigned* __restrict__ flg = flags + g * NSLICE;

    float c, h_last;
    {
        float hinit;
        if (firstchunk) { c = 0.f; hinit = 0.f; }
        else { c = cstate[bg * U_DIM + ug]; hinit = hstate[bg * U_DIM + ug]; }
        h_last = hinit;
        Hgrp[4096 + row * 256 + ug] = __float2half_rn(hinit);   // h^{-1} -> slot 1
    }
    __syncthreads();   // includes vmcnt(0): h-init stores complete
    if (tid == 0)
        __hip_atomic_store(&flg[s], 1u, __ATOMIC_RELEASE, __HIP_MEMORY_SCOPE_AGENT);

    const int mrow = 4 * (l >> 4);               // D-layout base row for this lane
    const int colg = 256 * w + 16 * s + (l & 15);
    const int abase = ((l & 15) << 9) | ((l >> 4) << 4);
    const int asw = (l & 7) << 4;

    for (int tl = 0; tl < TC; ++tl) {
        const int rd = (tl & 1) ^ 1;   // slot holding h^{tl-1}
        const int wr = tl & 1;         // slot for h^{tl}

        // prefetch xz (MFMA-lane layout) and residual (epilogue layout)
        float xzv[4];
        #pragma unroll
        for (int r = 0; r < 4; ++r) {
            const int rg = 16 * g + mrow + r;
            xzv[r] = xz[(size_t)(rg * TC + tl) * G_DIM + colg];
        }
        const float rv = res ? res[(size_t)(bg * T_DIM + t0 + tl) * U_DIM + ug] : 0.0f;

        // ---- wait for all slices' h^{tl-1} ----
        if (tid < NSLICE) {
            while (__hip_atomic_load(&flg[tid], __ATOMIC_ACQUIRE,
                                     __HIP_MEMORY_SCOPE_AGENT) < (unsigned)(tl + 1))
                __builtin_amdgcn_s_sleep(1);
        }
        __syncthreads();

        // ---- stage H (8 KB) into LDS with XOR swizzle ----
        {
            const uint4* src = (const uint4*)(Hgrp + rd * 4096);
            const uint4 a  = src[tid * 2];
            const uint4 b2 = src[tid * 2 + 1];
            const int lin = tid * 32;
            const int sw = ((lin >> 9) & 7) << 4;
            *(uint4*)((char*)Hlds + (lin ^ sw)) = a;
            *(uint4*)((char*)Hlds + ((lin + 16) ^ sw)) = b2;
        }
        __syncthreads();

        // ---- MFMA over K=256 (8 k-tiles, 2 independent chains) ----
        f32x4 acc0 = {0.f, 0.f, 0.f, 0.f}, acc1 = {0.f, 0.f, 0.f, 0.f};
        {
            const char* hb = (const char*)Hlds;
            #pragma unroll
            for (int kt = 0; kt < 8; kt += 2) {
                const uint4 ha = *(const uint4*)(hb + ((abase | (kt << 6)) ^ asw));
                const uint4 hc = *(const uint4*)(hb + ((abase | ((kt + 1) << 6)) ^ asw));
                acc0 = __builtin_amdgcn_mfma_f32_16x16x32_f16(
                    __builtin_bit_cast(f16x8, ha), __builtin_bit_cast(f16x8, bf[kt]),
                    acc0, 0, 0, 0);
                acc1 = __builtin_amdgcn_mfma_f32_16x16x32_f16(
                    __builtin_bit_cast(f16x8, hc), __builtin_bit_cast(f16x8, bf[kt + 1]),
                    acc1, 0, 0, 0);
            }
        }

        // ---- activation into zg (gate w, rows mrow..mrow+3, unit l&15) ----
        #pragma unroll
        for (int r = 0; r < 4; ++r) {
            const float z = acc0[r] + acc1[r] + xzv[r];
            zg[w][mrow + r][l & 15] = (w == 2) ? ftanh(z) : fsig(z);
        }
        __syncthreads();

        // ---- per-(row,unit) state update; c stays in a register ----
        {
            const float iv = zg[0][row][un];
            const float fv = zg[1][row][un];
            const float gv = zg[2][row][un];
            const float ov = zg[3][row][un];
            c = fv * c + iv * gv;
            const float hh = ov * ftanh(c);
            const __half hq = __float2half_rn(hh);
            h_last = __half2float(hq);
            Hgrp[wr * 4096 + row * 256 + ug] = hq;
            if (outseq)
                outseq[(size_t)(bg * T_DIM + t0 + tl) * U_DIM + ug] = hh + rv;
        }
        __syncthreads();   // vmcnt(0): all publish stores complete
        if (tid == 0)
            __hip_atomic_store(&flg[s], (unsigned)(tl + 2), __ATOMIC_RELEASE,
                               __HIP_MEMORY_SCOPE_AGENT);
    }

    hstate[bg * U_DIM + ug] = h_last;
    cstate[bg * U_DIM + ug] = c;
}

// ---------------------------------------------------------------------------
// GEMM: out[m, :] = A[row(m), :] @ W + bias, for one T-chunk. (unchanged)
// ---------------------------------------------------------------------------
__global__ __launch_bounds__(256)
void gemm_proj(const float* __restrict__ A, const float* __restrict__ W,
               const float* __restrict__ bias, float* __restrict__ out,
               int t0)
{
    __shared__ float As[16][64];
    __shared__ float Bs[16][64];

    const int tid = threadIdx.x;
    const int bm = blockIdx.y * 64;
    const int bn = blockIdx.x * 64;

    const int arow = tid >> 2;
    const int acol = (tid & 3) << 2;
    const int m_local = bm + arow;
    const int b  = m_local >> 7;
    const int tl = m_local & (TC - 1);
    const float* arow_ptr = A + (size_t)(b * T_DIM + t0 + tl) * U_DIM;

    const int brow = tid >> 4;
    const int bcol = (tid & 15) << 2;

    const int tr = tid >> 4;
    const int tc = tid & 15;

    float acc[4][4] = {};

    for (int k0 = 0; k0 < U_DIM; k0 += 16) {
        const float4 a4 = *(const float4*)(arow_ptr + k0 + acol);
        const float4 b4 = *(const float4*)(W + (size_t)(k0 + brow) * G_DIM + bn + bcol);
        As[acol + 0][arow] = a4.x;
        As[acol + 1][arow] = a4.y;
        As[acol + 2][arow] = a4.z;
        As[acol + 3][arow] = a4.w;
        *(float4*)&Bs[brow][bcol] = b4;
        __syncthreads();
        #pragma unroll
        for (int k = 0; k < 16; ++k) {
            const float4 av = *(const float4*)&As[k][tr << 2];
            const float4 bv = *(const float4*)&Bs[k][tc << 2];
            const float a_[4] = {av.x, av.y, av.z, av.w};
            const float b_[4] = {bv.x, bv.y, bv.z, bv.w};
            #pragma unroll
            for (int i = 0; i < 4; ++i)
                #pragma unroll
                for (int j = 0; j < 4; ++j)
                    acc[i][j] += a_[i] * b_[j];
        }
        __syncthreads();
    }

    const int oc = bn + (tc << 2);
    const float4 bia = *(const float4*)(bias + oc);
    #pragma unroll
    for (int i = 0; i < 4; ++i) {
        const int m = bm + (tr << 2) + i;
        float4 o;
        o.x = acc[i][0] + bia.x;
        o.y = acc[i][1] + bia.y;
        o.z = acc[i][2] + bia.z;
        o.w = acc[i][3] + bia.w;
        *(float4*)(out + (size_t)m * G_DIM + oc) = o;
    }
}

// ---------------------------------------------------------------------------
// Final: y[b,o] = sum_j (h1[b,j] + h2[b, j%256]) * Wd[j,o] + bd[o]  (unchanged)
// ---------------------------------------------------------------------------
__global__ __launch_bounds__(256)
void final_proj(const float* __restrict__ h1, const float* __restrict__ h2,
                const float* __restrict__ Wd, const float* __restrict__ bd,
                float* __restrict__ y)
{
    const int b = blockIdx.x;
    const int tid = threadIdx.x;
    const int JTOT = T_DIM * U_DIM;   // 131072

    float a0 = 0.f, a1 = 0.f, a2 = 0.f, a3 = 0.f;
    const float* hb = h1 + (size_t)b * JTOT;
    const float* h2b = h2 + (size_t)b * U_DIM;

    for (int j = tid; j < JTOT; j += 256) {
        const float v = hb[j] + h2b[j & (U_DIM - 1)];
        const float4 w = *(const float4*)&Wd[(size_t)j * 4];
        a0 += v * w.x;
        a1 += v * w.y;
        a2 += v * w.z;
        a3 += v * w.w;
    }

    __shared__ float red[256][4];
    red[tid][0] = a0; red[tid][1] = a1; red[tid][2] = a2; red[tid][3] = a3;
    __syncthreads();
    for (int s = 128; s > 0; s >>= 1) {
        if (tid < s) {
            #pragma unroll
            for (int o = 0; o < 4; ++o) red[tid][o] += red[tid + s][o];
        }
        __syncthreads();
    }
    if (tid < 4) y[b * 4 + tid] = red[0][tid] + bd[tid];
}

// ---------------------------------------------------------------------------
extern "C" void kernel_launch(void* const* d_in, const int* in_sizes, int n_in,
                              void* d_out, int out_size, void* d_ws, size_t ws_size,
                              hipStream_t stream)
{
    (void)in_sizes; (void)n_in; (void)out_size; (void)ws_size;

    const float* x  = (const float*)d_in[0];
    const float* Wr = (const float*)d_in[1];
    const float* Ur = (const float*)d_in[2];
    const float* br = (const float*)d_in[3];
    const float* Wn = (const float*)d_in[4];
    const float* Un = (const float*)d_in[5];
    const float* bn = (const float*)d_in[6];
    const float* Wd = (const float*)d_in[7];
    const float* bd = (const float*)d_in[8];
    float* y = (float*)d_out;

    float* ws = (float*)d_ws;
    const size_t CHUNK_ELEMS = (size_t)B_DIM * TC * G_DIM;      // 8,388,608
    const size_t SEQ_ELEMS   = (size_t)B_DIM * T_DIM * U_DIM;   // 8,388,608
    const size_t BHID        = (size_t)B_DIM * U_DIM;           // 16,384
    float* xzbuf = ws;
    float* h0    = xzbuf + CHUNK_ELEMS;
    float* h1    = h0 + SEQ_ELEMS;
    float* hs    = h1 + SEQ_ELEMS;
    float* cs    = hs + BHID;
    uint4* Pr    = (uint4*)(cs + BHID);            // 32*1024 uint4 = 512 KB
    uint4* Pn    = Pr + (size_t)32 * G_DIM;        // 512 KB
    __half* Hxp  = (__half*)(Pn + (size_t)32 * G_DIM);   // 4 grp * 2 * 4096 halves = 64 KB
    unsigned* flagsp = (unsigned*)(Hxp + (size_t)NGRP * 2 * 4096);  // 64 u32
    // total ws use ~= 98.3 MiB

    // ---- pack recurrent weights to f16 (MFMA B-fragment granularity) ----
    pack_w<<<128, 256, 0, stream>>>(Ur, Pr);
    pack_w<<<128, 256, 0, stream>>>(Un, Pn);

    dim3 ggrid(G_DIM / 64, (B_DIM * TC) / 64);   // (16, 128)

    for (int layer = 0; layer < 3; ++layer) {
        const float* src  = (layer == 0) ? x  : ((layer == 1) ? h0 : h1);
        const float* Wp   = (layer < 2) ? Wr : Wn;
        const float* bp   = (layer < 2) ? br : bn;
        const uint4* Pw   = (layer < 2) ? Pr : Pn;
        const float* resp = (layer == 1) ? h0 : nullptr;
        float* outp       = (layer == 0) ? h0 : ((layer == 1) ? h1 : nullptr);

        for (int ch = 0; ch < NCHUNK; ++ch) {
            int t0 = ch * TC;
            gemm_proj<<<ggrid, 256, 0, stream>>>(src, Wp, bp, xzbuf, t0);

            hipMemsetAsync(flagsp, 0, NGRP * NSLICE * sizeof(unsigned), stream);

            const float* xzarg = xzbuf;
            int first = (ch == 0) ? 1 : 0;
            void* kargs[] = {
                (void*)&xzarg, (void*)&Pw, (void*)&resp, (void*)&outp,
                (void*)&hs, (void*)&cs, (void*)&Hxp, (void*)&flagsp,
                (void*)&t0, (void*)&first
            };
            hipLaunchCooperativeKernel((void*)lstm_mfma, dim3(NGRP * NSLICE),
                                       dim3(256), kargs, 0, stream);
        }
    }

    // ---- final projection ----
    final_proj<<<B_DIM, 256, 0, stream>>>(h1, hs, Wd, bd, y);
}

// Round 8
// 2288.567 us; speedup vs baseline: 2.8421x; 2.8421x over previous
//
#include <hip/hip_runtime.h>
#include <hip/hip_fp16.h>
#include <cstddef>
#include <cstdint>

#define U_DIM 256
#define G_DIM 1024          // 4*U
#define T_DIM 512
#define B_DIM 64
#define TC    64            // timesteps per chunk
#define NCHUNK (T_DIM / TC) // 8
#define NSLOT  (NCHUNK + 2) // 10 pipeline slots
#define BHID   (B_DIM * U_DIM)

// Weight residency split (32 groups of 8 k-values each = K=256)
// 512 threads/block, 2 columns per thread.
#define NG_TOT 32
#define NG_REG 24           // groups  0..23 -> regs (compiler holds what it will; rest remats from L2)
#define NG_LDS 8            // groups 24..31 -> LDS (128 KB)

typedef _Float16 half2v __attribute__((ext_vector_type(2)));

__device__ __forceinline__ float fsig(float x) {
    return 1.0f / (1.0f + __expf(-x));
}
__device__ __forceinline__ float ftanh(float x) {
    return 2.0f * fsig(2.0f * x) - 1.0f;
}

// ---------------------------------------------------------------------------
// Pack U [256,1024] fp32 -> P: [32 groups][1024 cols] of uint4.
// P[g][n] holds f16(U[8g+0..8g+7][n]) packed 2-per-u32.
// ---------------------------------------------------------------------------
__global__ __launch_bounds__(256)
void pack_w(const float* __restrict__ U, uint4* __restrict__ P)
{
    const int idx = blockIdx.x * 256 + threadIdx.x;   // 0..32767
    const int g = idx >> 10;
    const int n = idx & 1023;
    uint vals[4];
    #pragma unroll
    for (int j = 0; j < 4; ++j) {
        const int k = g * 8 + j * 2;
        const __half a = __float2half_rn(U[(size_t)k * G_DIM + n]);
        const __half b = __float2half_rn(U[(size_t)(k + 1) * G_DIM + n]);
        const unsigned short ua = __builtin_bit_cast(unsigned short, a);
        const unsigned short ub = __builtin_bit_cast(unsigned short, b);
        vals[j] = (uint)ua | ((uint)ub << 16);
    }
    P[idx] = make_uint4(vals[0], vals[1], vals[2], vals[3]);
}

// 8 MACs: acc += sum_j f16(h)[j] * f16(w)[j]   (both packed 2-per-u32)
__device__ __forceinline__ float mac8(float acc, uint4 w, uint4 h)
{
#if __has_builtin(__builtin_amdgcn_fdot2)
    acc = __builtin_amdgcn_fdot2(__builtin_bit_cast(half2v, h.x),
                                 __builtin_bit_cast(half2v, w.x), acc, false);
    acc = __builtin_amdgcn_fdot2(__builtin_bit_cast(half2v, h.y),
                                 __builtin_bit_cast(half2v, w.y), acc, false);
    acc = __builtin_amdgcn_fdot2(__builtin_bit_cast(half2v, h.z),
                                 __builtin_bit_cast(half2v, w.z), acc, false);
    acc = __builtin_amdgcn_fdot2(__builtin_bit_cast(half2v, h.w),
                                 __builtin_bit_cast(half2v, w.w), acc, false);
#else
    const uint wv[4] = {w.x, w.y, w.z, w.w};
    const uint hv[4] = {h.x, h.y, h.z, h.w};
    #pragma unroll
    for (int j = 0; j < 4; ++j) {
        const __half2 wp = __builtin_bit_cast(__half2, wv[j]);
        const __half2 hp = __builtin_bit_cast(__half2, hv[j]);
        acc += __half2float(hp.x) * __half2float(wp.x);
        acc += __half2float(hp.y) * __half2float(wp.y);
    }
#endif
    return acc;
}

// ---------------------------------------------------------------------------
// Pipelined sequential LSTM. Grid = 192 blocks (3 layer-lanes x 64 batch rows).
// Block: layer = bid>>6, b = bid&63; chunk c = slot - layer (skip if invalid).
// Per-CU structure identical to the proven round-5 kernel: 512 threads,
// 2 waves/SIMD, thread t owns gate-cols t and t+512, weights in regs+LDS,
// h as packed f16 in LDS, all xz/h0/h1 in f16.
// ---------------------------------------------------------------------------
__global__
__attribute__((amdgpu_flat_work_group_size(512, 512)))
__attribute__((amdgpu_waves_per_eu(2, 2)))
void lstm_pipe(int slot,
               const __half* __restrict__ xzAll,
               const uint4* __restrict__ Pr, const uint4* __restrict__ Pn,
               __half* __restrict__ h0, __half* __restrict__ h1,
               float* __restrict__ hsAll, float* __restrict__ csAll)
{
    const int layer = blockIdx.x >> 6;
    const int b     = blockIdx.x & 63;
    const int c     = slot - layer;
    if ((unsigned)c >= (unsigned)NCHUNK) return;
    const int t0 = c * TC;

    const uint4* __restrict__ P = (layer < 2) ? Pr : Pn;
    const __half* __restrict__ xzb =
        xzAll + (size_t)layer * (B_DIM * TC * G_DIM) + (size_t)b * TC * G_DIM;
    const __half* __restrict__ resb =
        (layer == 1) ? (h0 + (size_t)(b * T_DIM + t0) * U_DIM) : nullptr;
    __half* __restrict__ outb =
        (layer == 0) ? (h0 + (size_t)(b * T_DIM + t0) * U_DIM)
      : (layer == 1) ? (h1 + (size_t)(b * T_DIM + t0) * U_DIM) : nullptr;
    float* __restrict__ hstate = hsAll + (size_t)layer * BHID + b * U_DIM;
    float* __restrict__ cstate = csAll + (size_t)layer * BHID + b * U_DIM;

    const int t = threadIdx.x;      // 0..511
    const int n0 = t;               // column A
    const int n1 = t + 512;         // column B

    __shared__ __align__(16) uint hq[U_DIM / 2];   // h as packed f16 (512 B)
    __shared__ float csh[U_DIM];
    __shared__ float zsh[G_DIM];
    __shared__ uint4 wlds[NG_LDS][G_DIM];          // 128 KB

    // ---- load resident weights (one-time per dispatch) ----
    uint4 wA[NG_REG], wB[NG_REG];
    #pragma unroll
    for (int g = 0; g < NG_REG; ++g) {
        wA[g] = P[(size_t)g * G_DIM + n0];
        wB[g] = P[(size_t)g * G_DIM + n1];
    }
    #pragma unroll
    for (int g = 0; g < NG_LDS; ++g) {
        wlds[g][n0] = P[(size_t)(NG_REG + g) * G_DIM + n0];
        wlds[g][n1] = P[(size_t)(NG_REG + g) * G_DIM + n1];
    }

    if (t < U_DIM) {
        float hv, cv;
        if (c == 0) { hv = 0.0f; cv = 0.0f; }
        else        { hv = hstate[t]; cv = cstate[t]; }
        csh[t] = cv;
        ((__half*)hq)[t] = __float2half_rn(hv);
    }
    __syncthreads();

    float cur0 = __half2float(xzb[n0]);
    float cur1 = __half2float(xzb[n1]);
    float resv = (resb && t < U_DIM) ? __half2float(resb[t]) : 0.0f;

    for (int tl = 0; tl < TC; ++tl) {
        float acc0 = cur0;
        float acc1 = cur1;

        // prefetch next step's xz / residual (latency hides under the dots)
        const int tn = (tl + 1 < TC) ? (tl + 1) : (TC - 1);
        cur0 = __half2float(xzb[(size_t)tn * G_DIM + n0]);
        cur1 = __half2float(xzb[(size_t)tn * G_DIM + n1]);
        const float resn = (resb && t < U_DIM)
                         ? __half2float(resb[(size_t)tn * U_DIM + t]) : 0.0f;

        const uint4* __restrict__ hp = (const uint4*)hq;

        // register-resident groups
        #pragma unroll
        for (int g = 0; g < NG_REG; ++g) {
            const uint4 h4 = hp[g];
            acc0 = mac8(acc0, wA[g], h4);
            acc1 = mac8(acc1, wB[g], h4);
        }
        // LDS-resident groups
        #pragma unroll
        for (int g = 0; g < NG_LDS; ++g) {
            const uint4 h4 = hp[NG_REG + g];
            acc0 = mac8(acc0, wlds[g][n0], h4);
            acc1 = mac8(acc1, wlds[g][n1], h4);
        }

        // activations (wave-uniform branch: waves 0-3 have t<256)
        zsh[n0] = fsig(acc0);
        zsh[n1] = (t < U_DIM) ? ftanh(acc1) : fsig(acc1);
        __syncthreads();

        if (t < U_DIM) {
            const float iv = zsh[t];
            const float fv = zsh[t + 256];
            const float gv = zsh[t + 512];
            const float ov = zsh[t + 768];
            const float cc = fv * csh[t] + iv * gv;
            const float hh = ov * ftanh(cc);
            csh[t] = cc;
            ((__half*)hq)[t] = __float2half_rn(hh);
            if (outb) outb[(size_t)tl * U_DIM + t] = __float2half_rn(hh + resv);
        }
        resv = resn;
        __syncthreads();
    }

    if (t < U_DIM) {
        hstate[t] = __half2float(((const __half*)hq)[t]);
        cstate[t] = csh[t];
    }
}

// ---------------------------------------------------------------------------
// Fused per-slot input projections: grid (16, 64, 3); z = layer lane.
// Lane z computes chunk c = slot - z of layer z:
//   xz_z = A_z[chunk rows] @ W_z + bias_z   (A0 = x f32, A1 = h0 f16, A2 = h1 f16)
// Output xzAll[z] in f16. Tile 64x64, BK=16, 256 threads.
// ---------------------------------------------------------------------------
__global__ __launch_bounds__(256)
void gemm3(int slot,
           const float* __restrict__ x,
           const __half* __restrict__ h0, const __half* __restrict__ h1,
           const float* __restrict__ Wr, const float* __restrict__ Wn,
           const float* __restrict__ br, const float* __restrict__ bn,
           __half* __restrict__ xzAll)
{
    const int z = blockIdx.z;
    const int c = slot - z;
    if ((unsigned)c >= (unsigned)NCHUNK) return;
    const int t0 = c * TC;

    const float*  W    = (z < 2) ? Wr : Wn;
    const float*  bias = (z < 2) ? br : bn;
    const __half* Ah   = (z == 1) ? h0 : h1;   // used when z>0
    __half* out = xzAll + (size_t)z * (B_DIM * TC * G_DIM);

    __shared__ float As[16][64];
    __shared__ float Bs[16][64];

    const int tid = threadIdx.x;
    const int bm = blockIdx.y * 64;
    const int bn_ = blockIdx.x * 64;

    const int arow = tid >> 2;
    const int acol = (tid & 3) << 2;
    const int m_local = bm + arow;
    const int b  = m_local >> 6;          // / TC (=64)
    const int tl = m_local & (TC - 1);
    const size_t grow = (size_t)(b * T_DIM + t0 + tl) * U_DIM;

    const int brow = tid >> 4;
    const int bcol = (tid & 15) << 2;

    const int tr = tid >> 4;
    const int tc = tid & 15;

    float acc[4][4] = {};

    for (int k0 = 0; k0 < U_DIM; k0 += 16) {
        float av[4];
        if (z == 0) {
            const float4 a4 = *(const float4*)(x + grow + k0 + acol);
            av[0] = a4.x; av[1] = a4.y; av[2] = a4.z; av[3] = a4.w;
        } else {
            const ushort4 a4 = *(const ushort4*)(Ah + grow + k0 + acol);
            av[0] = __half2float(__builtin_bit_cast(__half, a4.x));
            av[1] = __half2float(__builtin_bit_cast(__half, a4.y));
            av[2] = __half2float(__builtin_bit_cast(__half, a4.z));
            av[3] = __half2float(__builtin_bit_cast(__half, a4.w));
        }
        const float4 b4 = *(const float4*)(W + (size_t)(k0 + brow) * G_DIM + bn_ + bcol);
        As[acol + 0][arow] = av[0];
        As[acol + 1][arow] = av[1];
        As[acol + 2][arow] = av[2];
        As[acol + 3][arow] = av[3];
        *(float4*)&Bs[brow][bcol] = b4;
        __syncthreads();
        #pragma unroll
        for (int k = 0; k < 16; ++k) {
            const float4 a2 = *(const float4*)&As[k][tr << 2];
            const float4 b2 = *(const float4*)&Bs[k][tc << 2];
            const float a_[4] = {a2.x, a2.y, a2.z, a2.w};
            const float b_[4] = {b2.x, b2.y, b2.z, b2.w};
            #pragma unroll
            for (int i = 0; i < 4; ++i)
                #pragma unroll
                for (int j = 0; j < 4; ++j)
                    acc[i][j] += a_[i] * b_[j];
        }
        __syncthreads();
    }

    const int oc = bn_ + (tc << 2);
    const float4 bia = *(const float4*)(bias + oc);
    #pragma unroll
    for (int i = 0; i < 4; ++i) {
        const int m = bm + (tr << 2) + i;
        ushort4 o;
        o.x = __builtin_bit_cast(unsigned short, __float2half_rn(acc[i][0] + bia.x));
        o.y = __builtin_bit_cast(unsigned short, __float2half_rn(acc[i][1] + bia.y));
        o.z = __builtin_bit_cast(unsigned short, __float2half_rn(acc[i][2] + bia.z));
        o.w = __builtin_bit_cast(unsigned short, __float2half_rn(acc[i][3] + bia.w));
        *(ushort4*)(out + (size_t)m * G_DIM + oc) = o;
    }
}

// ---------------------------------------------------------------------------
// Final: y[b,o] = sum_j (h1[b,j] + h2[b, j%256]) * Wd[j,o] + bd[o]
// h1 is f16 now; h2 (layer-2 last hidden state) is f32.
// ---------------------------------------------------------------------------
__global__ __launch_bounds__(256)
void final_proj(const __half* __restrict__ h1, const float* __restrict__ h2,
                const float* __restrict__ Wd, const float* __restrict__ bd,
                float* __restrict__ y)
{
    const int b = blockIdx.x;
    const int tid = threadIdx.x;
    const int JTOT = T_DIM * U_DIM;   // 131072

    float a0 = 0.f, a1 = 0.f, a2 = 0.f, a3 = 0.f;
    const __half* hb = h1 + (size_t)b * JTOT;
    const float* h2b = h2 + (size_t)b * U_DIM;

    for (int j = tid; j < JTOT; j += 256) {
        const float v = __half2float(hb[j]) + h2b[j & (U_DIM - 1)];
        const float4 w = *(const float4*)&Wd[(size_t)j * 4];
        a0 += v * w.x;
        a1 += v * w.y;
        a2 += v * w.z;
        a3 += v * w.w;
    }

    __shared__ float red[256][4];
    red[tid][0] = a0; red[tid][1] = a1; red[tid][2] = a2; red[tid][3] = a3;
    __syncthreads();
    for (int s = 128; s > 0; s >>= 1) {
        if (tid < s) {
            #pragma unroll
            for (int o = 0; o < 4; ++o) red[tid][o] += red[tid + s][o];
        }
        __syncthreads();
    }
    if (tid < 4) y[b * 4 + tid] = red[0][tid] + bd[tid];
}

// ---------------------------------------------------------------------------
extern "C" void kernel_launch(void* const* d_in, const int* in_sizes, int n_in,
                              void* d_out, int out_size, void* d_ws, size_t ws_size,
                              hipStream_t stream)
{
    (void)in_sizes; (void)n_in; (void)out_size; (void)ws_size;

    const float* x  = (const float*)d_in[0];
    const float* Wr = (const float*)d_in[1];
    const float* Ur = (const float*)d_in[2];
    const float* br = (const float*)d_in[3];
    const float* Wn = (const float*)d_in[4];
    const float* Un = (const float*)d_in[5];
    const float* bn = (const float*)d_in[6];
    const float* Wd = (const float*)d_in[7];
    const float* bd = (const float*)d_in[8];
    float* y = (float*)d_out;

    // ---- workspace layout (bytes) ----
    char* wp = (char*)d_ws;
    uint4* Pr = (uint4*)wp;                       wp += (size_t)NG_TOT * G_DIM * 16;  // 512 KB
    uint4* Pn = (uint4*)wp;                       wp += (size_t)NG_TOT * G_DIM * 16;  // 512 KB
    float* hsAll = (float*)wp;                    wp += (size_t)3 * BHID * 4;         // 196 KB
    float* csAll = (float*)wp;                    wp += (size_t)3 * BHID * 4;         // 196 KB
    __half* xzAll = (__half*)wp;                  wp += (size_t)3 * B_DIM * TC * G_DIM * 2;  // 25.2 MB
    __half* h0 = (__half*)wp;                     wp += (size_t)B_DIM * T_DIM * U_DIM * 2;   // 16.8 MB
    __half* h1 = (__half*)wp;                     wp += (size_t)B_DIM * T_DIM * U_DIM * 2;   // 16.8 MB
    // total ~60.3 MB

    // ---- pack recurrent weights to f16 ----
    pack_w<<<128, 256, 0, stream>>>(Ur, Pr);
    pack_w<<<128, 256, 0, stream>>>(Un, Pn);

    // ---- software-pipelined layer x chunk wavefront ----
    dim3 ggrid(G_DIM / 64, (B_DIM * TC) / 64, 3);   // (16, 64, 3)
    for (int slot = 0; slot < NSLOT; ++slot) {
        gemm3<<<ggrid, 256, 0, stream>>>(slot, x, h0, h1, Wr, Wn, br, bn, xzAll);
        lstm_pipe<<<3 * B_DIM, 512, 0, stream>>>(slot, xzAll, Pr, Pn,
                                                 h0, h1, hsAll, csAll);
    }

    // ---- final projection (h2 = layer-2 final hidden state) ----
    final_proj<<<B_DIM, 256, 0, stream>>>(h1, hsAll + 2 * BHID, Wd, bd, y);
}

// Round 9
// 1951.425 us; speedup vs baseline: 3.3331x; 1.1728x over previous
//
#include <hip/hip_runtime.h>
#include <hip/hip_fp16.h>
#include <cstddef>
#include <cstdint>

#define U_DIM 256
#define G_DIM 1024          // 4*U
#define T_DIM 512
#define B_DIM 64
#define TC    64            // timesteps per chunk
#define NCHUNK (T_DIM / TC) // 8
#define NSLOT  (NCHUNK + 2) // 10 pipeline slots
#define BHID   (B_DIM * U_DIM)
#define NPART  8            // final-proj j-range parts

// Weight residency split (32 groups of 8 k-values each = K=256)
// 512 threads/block, 2 columns per thread. 2 waves/SIMD -> 256-reg cap.
// Pinned demand: 23*2*4 = 184 regs + ~40 working = ~224 <= 256.
#define NG_TOT 32
#define NG_REG 23           // groups  0..22 -> regs (pinned)
#define NG_LDS 9            // groups 23..31 -> LDS (147 KB)

typedef _Float16 half2v __attribute__((ext_vector_type(2)));

__device__ __forceinline__ float fsig(float x) {
    return 1.0f / (1.0f + __expf(-x));
}
__device__ __forceinline__ float ftanh(float x) {
    return 2.0f * fsig(2.0f * x) - 1.0f;
}

#define PIN4(v) asm("" : "+v"(v.x), "+v"(v.y), "+v"(v.z), "+v"(v.w))

// ---------------------------------------------------------------------------
// Pack U [256,1024] fp32 -> P: [32 groups][1024 cols] of uint4.
// P[g][n] holds f16(U[8g+0..8g+7][n]) packed 2-per-u32.
// ---------------------------------------------------------------------------
__global__ __launch_bounds__(256)
void pack_w(const float* __restrict__ U, uint4* __restrict__ P)
{
    const int idx = blockIdx.x * 256 + threadIdx.x;   // 0..32767
    const int g = idx >> 10;
    const int n = idx & 1023;
    uint vals[4];
    #pragma unroll
    for (int j = 0; j < 4; ++j) {
        const int k = g * 8 + j * 2;
        const __half a = __float2half_rn(U[(size_t)k * G_DIM + n]);
        const __half b = __float2half_rn(U[(size_t)(k + 1) * G_DIM + n]);
        const unsigned short ua = __builtin_bit_cast(unsigned short, a);
        const unsigned short ub = __builtin_bit_cast(unsigned short, b);
        vals[j] = (uint)ua | ((uint)ub << 16);
    }
    P[idx] = make_uint4(vals[0], vals[1], vals[2], vals[3]);
}

// 8 MACs: acc += sum_j f16(h)[j] * f16(w)[j]   (both packed 2-per-u32)
__device__ __forceinline__ float mac8(float acc, uint4 w, uint4 h)
{
#if __has_builtin(__builtin_amdgcn_fdot2)
    acc = __builtin_amdgcn_fdot2(__builtin_bit_cast(half2v, h.x),
                                 __builtin_bit_cast(half2v, w.x), acc, false);
    acc = __builtin_amdgcn_fdot2(__builtin_bit_cast(half2v, h.y),
                                 __builtin_bit_cast(half2v, w.y), acc, false);
    acc = __builtin_amdgcn_fdot2(__builtin_bit_cast(half2v, h.z),
                                 __builtin_bit_cast(half2v, w.z), acc, false);
    acc = __builtin_amdgcn_fdot2(__builtin_bit_cast(half2v, h.w),
                                 __builtin_bit_cast(half2v, w.w), acc, false);
#else
    const uint wv[4] = {w.x, w.y, w.z, w.w};
    const uint hv[4] = {h.x, h.y, h.z, h.w};
    #pragma unroll
    for (int j = 0; j < 4; ++j) {
        const __half2 wp = __builtin_bit_cast(__half2, wv[j]);
        const __half2 hp = __builtin_bit_cast(__half2, hv[j]);
        acc += __half2float(hp.x) * __half2float(wp.x);
        acc += __half2float(hp.y) * __half2float(wp.y);
    }
#endif
    return acc;
}

// ---------------------------------------------------------------------------
// Pipelined sequential LSTM. Grid = 192 blocks (3 layer-lanes x 64 batch rows).
// Block: layer = bid>>6, b = bid&63; chunk c = slot - layer (skip if invalid).
// 512 threads, 2 waves/SIMD (256-reg cap); weights PINNED in regs + LDS.
// ---------------------------------------------------------------------------
__global__
__attribute__((amdgpu_flat_work_group_size(512, 512)))
__attribute__((amdgpu_waves_per_eu(2, 2)))
void lstm_pipe(int slot,
               const __half* __restrict__ xzAll,
               const uint4* __restrict__ Pr, const uint4* __restrict__ Pn,
               __half* __restrict__ h0, __half* __restrict__ h1,
               float* __restrict__ hsAll, float* __restrict__ csAll)
{
    const int layer = blockIdx.x >> 6;
    const int b     = blockIdx.x & 63;
    const int c     = slot - layer;
    if ((unsigned)c >= (unsigned)NCHUNK) return;
    const int t0 = c * TC;

    const uint4* __restrict__ P = (layer < 2) ? Pr : Pn;
    const __half* __restrict__ xzb =
        xzAll + (size_t)layer * (B_DIM * TC * G_DIM) + (size_t)b * TC * G_DIM;
    const __half* __restrict__ resb =
        (layer == 1) ? (h0 + (size_t)(b * T_DIM + t0) * U_DIM) : nullptr;
    __half* __restrict__ outb =
        (layer == 0) ? (h0 + (size_t)(b * T_DIM + t0) * U_DIM)
      : (layer == 1) ? (h1 + (size_t)(b * T_DIM + t0) * U_DIM) : nullptr;
    float* __restrict__ hstate = hsAll + (size_t)layer * BHID + b * U_DIM;
    float* __restrict__ cstate = csAll + (size_t)layer * BHID + b * U_DIM;

    const int t = threadIdx.x;      // 0..511
    const int n0 = t;               // column A
    const int n1 = t + 512;         // column B

    __shared__ __align__(16) uint hq[U_DIM / 2];   // h as packed f16 (512 B)
    __shared__ float csh[U_DIM];
    __shared__ float zsh[G_DIM];
    __shared__ uint4 wlds[NG_LDS][G_DIM];          // 147 KB

    // ---- load resident weights, then PIN so they cannot be rematerialized ----
    uint4 wA[NG_REG], wB[NG_REG];
    #pragma unroll
    for (int g = 0; g < NG_REG; ++g) {
        wA[g] = P[(size_t)g * G_DIM + n0];
        wB[g] = P[(size_t)g * G_DIM + n1];
    }
    #pragma unroll
    for (int g = 0; g < NG_REG; ++g) { PIN4(wA[g]); PIN4(wB[g]); }
    #pragma unroll
    for (int g = 0; g < NG_LDS; ++g) {
        wlds[g][n0] = P[(size_t)(NG_REG + g) * G_DIM + n0];
        wlds[g][n1] = P[(size_t)(NG_REG + g) * G_DIM + n1];
    }

    if (t < U_DIM) {
        float hv, cv;
        if (c == 0) { hv = 0.0f; cv = 0.0f; }
        else        { hv = hstate[t]; cv = cstate[t]; }
        csh[t] = cv;
        ((__half*)hq)[t] = __float2half_rn(hv);
    }
    __syncthreads();

    float cur0 = __half2float(xzb[n0]);
    float cur1 = __half2float(xzb[n1]);
    float resv = (resb && t < U_DIM) ? __half2float(resb[t]) : 0.0f;

    for (int tl = 0; tl < TC; ++tl) {
        float acc0 = cur0;
        float acc1 = cur1;

        // prefetch next step's xz / residual (latency hides under the dots)
        const int tn = (tl + 1 < TC) ? (tl + 1) : (TC - 1);
        cur0 = __half2float(xzb[(size_t)tn * G_DIM + n0]);
        cur1 = __half2float(xzb[(size_t)tn * G_DIM + n1]);
        const float resn = (resb && t < U_DIM)
                         ? __half2float(resb[(size_t)tn * U_DIM + t]) : 0.0f;

        const uint4* __restrict__ hp = (const uint4*)hq;

        // register-resident groups
        #pragma unroll
        for (int g = 0; g < NG_REG; ++g) {
            const uint4 h4 = hp[g];
            acc0 = mac8(acc0, wA[g], h4);
            acc1 = mac8(acc1, wB[g], h4);
        }
        // LDS-resident groups
        #pragma unroll
        for (int g = 0; g < NG_LDS; ++g) {
            const uint4 h4 = hp[NG_REG + g];
            acc0 = mac8(acc0, wlds[g][n0], h4);
            acc1 = mac8(acc1, wlds[g][n1], h4);
        }

        // activations (wave-uniform branch: waves 0-3 have t<256)
        zsh[n0] = fsig(acc0);
        zsh[n1] = (t < U_DIM) ? ftanh(acc1) : fsig(acc1);
        __syncthreads();

        if (t < U_DIM) {
            const float iv = zsh[t];
            const float fv = zsh[t + 256];
            const float gv = zsh[t + 512];
            const float ov = zsh[t + 768];
            const float cc = fv * csh[t] + iv * gv;
            const float hh = ov * ftanh(cc);
            csh[t] = cc;
            ((__half*)hq)[t] = __float2half_rn(hh);
            if (outb) outb[(size_t)tl * U_DIM + t] = __float2half_rn(hh + resv);
        }
        resv = resn;
        __syncthreads();
    }

    if (t < U_DIM) {
        hstate[t] = __half2float(((const __half*)hq)[t]);
        cstate[t] = csh[t];
    }
}

// ---------------------------------------------------------------------------
// Fused per-slot input projections: grid (16, 64, 3); z = layer lane.
// ---------------------------------------------------------------------------
__global__ __launch_bounds__(256)
void gemm3(int slot,
           const float* __restrict__ x,
           const __half* __restrict__ h0, const __half* __restrict__ h1,
           const float* __restrict__ Wr, const float* __restrict__ Wn,
           const float* __restrict__ br, const float* __restrict__ bn,
           __half* __restrict__ xzAll)
{
    const int z = blockIdx.z;
    const int c = slot - z;
    if ((unsigned)c >= (unsigned)NCHUNK) return;
    const int t0 = c * TC;

    const float*  W    = (z < 2) ? Wr : Wn;
    const float*  bias = (z < 2) ? br : bn;
    const __half* Ah   = (z == 1) ? h0 : h1;   // used when z>0
    __half* out = xzAll + (size_t)z * (B_DIM * TC * G_DIM);

    __shared__ float As[16][64];
    __shared__ float Bs[16][64];

    const int tid = threadIdx.x;
    const int bm = blockIdx.y * 64;
    const int bn_ = blockIdx.x * 64;

    const int arow = tid >> 2;
    const int acol = (tid & 3) << 2;
    const int m_local = bm + arow;
    const int b  = m_local >> 6;          // / TC (=64)
    const int tl = m_local & (TC - 1);
    const size_t grow = (size_t)(b * T_DIM + t0 + tl) * U_DIM;

    const int brow = tid >> 4;
    const int bcol = (tid & 15) << 2;

    const int tr = tid >> 4;
    const int tc = tid & 15;

    float acc[4][4] = {};

    for (int k0 = 0; k0 < U_DIM; k0 += 16) {
        float av[4];
        if (z == 0) {
            const float4 a4 = *(const float4*)(x + grow + k0 + acol);
            av[0] = a4.x; av[1] = a4.y; av[2] = a4.z; av[3] = a4.w;
        } else {
            const ushort4 a4 = *(const ushort4*)(Ah + grow + k0 + acol);
            av[0] = __half2float(__builtin_bit_cast(__half, a4.x));
            av[1] = __half2float(__builtin_bit_cast(__half, a4.y));
            av[2] = __half2float(__builtin_bit_cast(__half, a4.z));
            av[3] = __half2float(__builtin_bit_cast(__half, a4.w));
        }
        const float4 b4 = *(const float4*)(W + (size_t)(k0 + brow) * G_DIM + bn_ + bcol);
        As[acol + 0][arow] = av[0];
        As[acol + 1][arow] = av[1];
        As[acol + 2][arow] = av[2];
        As[acol + 3][arow] = av[3];
        *(float4*)&Bs[brow][bcol] = b4;
        __syncthreads();
        #pragma unroll
        for (int k = 0; k < 16; ++k) {
            const float4 a2 = *(const float4*)&As[k][tr << 2];
            const float4 b2 = *(const float4*)&Bs[k][tc << 2];
            const float a_[4] = {a2.x, a2.y, a2.z, a2.w};
            const float b_[4] = {b2.x, b2.y, b2.z, b2.w};
            #pragma unroll
            for (int i = 0; i < 4; ++i)
                #pragma unroll
                for (int j = 0; j < 4; ++j)
                    acc[i][j] += a_[i] * b_[j];
        }
        __syncthreads();
    }

    const int oc = bn_ + (tc << 2);
    const float4 bia = *(const float4*)(bias + oc);
    #pragma unroll
    for (int i = 0; i < 4; ++i) {
        const int m = bm + (tr << 2) + i;
        ushort4 o;
        o.x = __builtin_bit_cast(unsigned short, __float2half_rn(acc[i][0] + bia.x));
        o.y = __builtin_bit_cast(unsigned short, __float2half_rn(acc[i][1] + bia.y));
        o.z = __builtin_bit_cast(unsigned short, __float2half_rn(acc[i][2] + bia.z));
        o.w = __builtin_bit_cast(unsigned short, __float2half_rn(acc[i][3] + bia.w));
        *(ushort4*)(out + (size_t)m * G_DIM + oc) = o;
    }
}

// ---------------------------------------------------------------------------
// Final projection, stage A: grid (64 b, 8 parts) x 256 threads.
// partials[b][p][o] = sum over j in part p of (h1[b,j] + h2[b,j%256]) * Wd[j,o]
// Each thread handles 8 consecutive j per iteration (vector loads).
// ---------------------------------------------------------------------------
__global__ __launch_bounds__(256)
void final_partial(const __half* __restrict__ h1, const float* __restrict__ h2,
                   const float* __restrict__ Wd, float* __restrict__ partials)
{
    const int b = blockIdx.x;
    const int p = blockIdx.y;
    const int tid = threadIdx.x;
    const int JTOT = T_DIM * U_DIM;          // 131072
    const int JPART = JTOT / NPART;          // 16384

    const __half* hb = h1 + (size_t)b * JTOT;
    const float* h2b = h2 + (size_t)b * U_DIM;

    float a0 = 0.f, a1 = 0.f, a2 = 0.f, a3 = 0.f;

    for (int j = p * JPART + tid * 8; j < (p + 1) * JPART; j += 256 * 8) {
        const uint4 hv = *(const uint4*)(hb + j);
        const int m = j & (U_DIM - 1);
        const float4 s0 = *(const float4*)(h2b + m);
        const float4 s1 = *(const float4*)(h2b + m + 4);
        float v[8];
        {
            const __half2 p0 = __builtin_bit_cast(__half2, hv.x);
            const __half2 p1 = __builtin_bit_cast(__half2, hv.y);
            const __half2 p2 = __builtin_bit_cast(__half2, hv.z);
            const __half2 p3 = __builtin_bit_cast(__half2, hv.w);
            v[0] = __half2float(p0.x) + s0.x;
            v[1] = __half2float(p0.y) + s0.y;
            v[2] = __half2float(p1.x) + s0.z;
            v[3] = __half2float(p1.y) + s0.w;
            v[4] = __half2float(p2.x) + s1.x;
            v[5] = __half2float(p2.y) + s1.y;
            v[6] = __half2float(p3.x) + s1.z;
            v[7] = __half2float(p3.y) + s1.w;
        }
        #pragma unroll
        for (int u = 0; u < 8; ++u) {
            const float4 w = *(const float4*)&Wd[(size_t)(j + u) * 4];
            a0 += v[u] * w.x;
            a1 += v[u] * w.y;
            a2 += v[u] * w.z;
            a3 += v[u] * w.w;
        }
    }

    __shared__ float red[256][4];
    red[tid][0] = a0; red[tid][1] = a1; red[tid][2] = a2; red[tid][3] = a3;
    __syncthreads();
    for (int s = 128; s > 0; s >>= 1) {
        if (tid < s) {
            #pragma unroll
            for (int o = 0; o < 4; ++o) red[tid][o] += red[tid + s][o];
        }
        __syncthreads();
    }
    if (tid < 4) partials[((size_t)b * NPART + p) * 4 + tid] = red[0][tid];
}

// Stage B: one block; thread tid -> (b = tid>>2, o = tid&3)
__global__ __launch_bounds__(256)
void final_reduce(const float* __restrict__ partials, const float* __restrict__ bd,
                  float* __restrict__ y)
{
    const int tid = threadIdx.x;
    const int b = tid >> 2;
    const int o = tid & 3;
    float s = bd[o];
    #pragma unroll
    for (int p = 0; p < NPART; ++p)
        s += partials[((size_t)b * NPART + p) * 4 + o];
    y[b * 4 + o] = s;
}

// ---------------------------------------------------------------------------
extern "C" void kernel_launch(void* const* d_in, const int* in_sizes, int n_in,
                              void* d_out, int out_size, void* d_ws, size_t ws_size,
                              hipStream_t stream)
{
    (void)in_sizes; (void)n_in; (void)out_size; (void)ws_size;

    const float* x  = (const float*)d_in[0];
    const float* Wr = (const float*)d_in[1];
    const float* Ur = (const float*)d_in[2];
    const float* br = (const float*)d_in[3];
    const float* Wn = (const float*)d_in[4];
    const float* Un = (const float*)d_in[5];
    const float* bn = (const float*)d_in[6];
    const float* Wd = (const float*)d_in[7];
    const float* bd = (const float*)d_in[8];
    float* y = (float*)d_out;

    // ---- workspace layout (bytes) ----
    char* wp = (char*)d_ws;
    uint4* Pr = (uint4*)wp;                       wp += (size_t)NG_TOT * G_DIM * 16;  // 512 KB
    uint4* Pn = (uint4*)wp;                       wp += (size_t)NG_TOT * G_DIM * 16;  // 512 KB
    float* hsAll = (float*)wp;                    wp += (size_t)3 * BHID * 4;         // 196 KB
    float* csAll = (float*)wp;                    wp += (size_t)3 * BHID * 4;         // 196 KB
    float* partials = (float*)wp;                 wp += (size_t)B_DIM * NPART * 4 * 4; // 8 KB
    __half* xzAll = (__half*)wp;                  wp += (size_t)3 * B_DIM * TC * G_DIM * 2;  // 25.2 MB
    __half* h0 = (__half*)wp;                     wp += (size_t)B_DIM * T_DIM * U_DIM * 2;   // 16.8 MB
    __half* h1 = (__half*)wp;                     wp += (size_t)B_DIM * T_DIM * U_DIM * 2;   // 16.8 MB
    // total ~60.3 MB

    // ---- pack recurrent weights to f16 ----
    pack_w<<<128, 256, 0, stream>>>(Ur, Pr);
    pack_w<<<128, 256, 0, stream>>>(Un, Pn);

    // ---- software-pipelined layer x chunk wavefront ----
    dim3 ggrid(G_DIM / 64, (B_DIM * TC) / 64, 3);   // (16, 64, 3)
    for (int slot = 0; slot < NSLOT; ++slot) {
        gemm3<<<ggrid, 256, 0, stream>>>(slot, x, h0, h1, Wr, Wn, br, bn, xzAll);
        lstm_pipe<<<3 * B_DIM, 512, 0, stream>>>(slot, xzAll, Pr, Pn,
                                                 h0, h1, hsAll, csAll);
    }

    // ---- final projection (h2 = layer-2 final hidden state) ----
    final_partial<<<dim3(B_DIM, NPART), 256, 0, stream>>>(h1, hsAll + 2 * BHID,
                                                          Wd, partials);
    final_reduce<<<1, 256, 0, stream>>>(partials, bd, y);
}

// Round 10
// 1700.271 us; speedup vs baseline: 3.8255x; 1.1477x over previous
//
#include <hip/hip_runtime.h>
#include <hip/hip_fp16.h>
#include <cstddef>
#include <cstdint>

#define U_DIM 256
#define G_DIM 1024          // 4*U
#define T_DIM 512
#define B_DIM 64
#define TC    64            // timesteps per chunk
#define NCHUNK (T_DIM / TC) // 8
#define NSLOT  (NCHUNK + 2) // 10 pipeline slots
#define BHID   (B_DIM * U_DIM)
#define NPART  8            // final-proj j-range parts

// Weight residency split for the lstm kernel (unchanged from round 9)
#define NG_TOT 32
#define NG_REG 23
#define NG_LDS 9

typedef _Float16 half2v __attribute__((ext_vector_type(2)));
typedef _Float16 f16x8  __attribute__((ext_vector_type(8)));
typedef float    f32x4  __attribute__((ext_vector_type(4)));

__device__ __forceinline__ float fsig(float x) {
    return 1.0f / (1.0f + __expf(-x));
}
__device__ __forceinline__ float ftanh(float x) {
    return 2.0f * fsig(2.0f * x) - 1.0f;
}

#define PIN4(v) asm("" : "+v"(v.x), "+v"(v.y), "+v"(v.z), "+v"(v.w))

// ---------------------------------------------------------------------------
// Pack U [256,1024] fp32 -> P: [32 groups][1024 cols] of uint4.
// P[g][n] holds f16(U[8g+0..8g+7][n]) packed 2-per-u32.
// (Also the MFMA B-fragment layout: lane reads P[(4kt + (l>>4))*1024 + col].)
// ---------------------------------------------------------------------------
__global__ __launch_bounds__(256)
void pack_w(const float* __restrict__ U, uint4* __restrict__ P)
{
    const int idx = blockIdx.x * 256 + threadIdx.x;   // 0..32767
    const int g = idx >> 10;
    const int n = idx & 1023;
    uint vals[4];
    #pragma unroll
    for (int j = 0; j < 4; ++j) {
        const int k = g * 8 + j * 2;
        const __half a = __float2half_rn(U[(size_t)k * G_DIM + n]);
        const __half b = __float2half_rn(U[(size_t)(k + 1) * G_DIM + n]);
        const unsigned short ua = __builtin_bit_cast(unsigned short, a);
        const unsigned short ub = __builtin_bit_cast(unsigned short, b);
        vals[j] = (uint)ua | ((uint)ub << 16);
    }
    P[idx] = make_uint4(vals[0], vals[1], vals[2], vals[3]);
}

// Pack x f32 -> f16, 8 elems/thread.
__global__ __launch_bounds__(256)
void pack_x(const float* __restrict__ x, __half* __restrict__ xh)
{
    const size_t i = ((size_t)blockIdx.x * 256 + threadIdx.x) * 8;
    const float4 a = *(const float4*)(x + i);
    const float4 b = *(const float4*)(x + i + 4);
    ushort4 o0, o1;
    o0.x = __builtin_bit_cast(unsigned short, __float2half_rn(a.x));
    o0.y = __builtin_bit_cast(unsigned short, __float2half_rn(a.y));
    o0.z = __builtin_bit_cast(unsigned short, __float2half_rn(a.z));
    o0.w = __builtin_bit_cast(unsigned short, __float2half_rn(a.w));
    o1.x = __builtin_bit_cast(unsigned short, __float2half_rn(b.x));
    o1.y = __builtin_bit_cast(unsigned short, __float2half_rn(b.y));
    o1.z = __builtin_bit_cast(unsigned short, __float2half_rn(b.z));
    o1.w = __builtin_bit_cast(unsigned short, __float2half_rn(b.w));
    *(ushort4*)(xh + i) = o0;
    *(ushort4*)(xh + i + 4) = o1;
}

// 8 MACs: acc += sum_j f16(h)[j] * f16(w)[j]   (both packed 2-per-u32)
__device__ __forceinline__ float mac8(float acc, uint4 w, uint4 h)
{
#if __has_builtin(__builtin_amdgcn_fdot2)
    acc = __builtin_amdgcn_fdot2(__builtin_bit_cast(half2v, h.x),
                                 __builtin_bit_cast(half2v, w.x), acc, false);
    acc = __builtin_amdgcn_fdot2(__builtin_bit_cast(half2v, h.y),
                                 __builtin_bit_cast(half2v, w.y), acc, false);
    acc = __builtin_amdgcn_fdot2(__builtin_bit_cast(half2v, h.z),
                                 __builtin_bit_cast(half2v, w.z), acc, false);
    acc = __builtin_amdgcn_fdot2(__builtin_bit_cast(half2v, h.w),
                                 __builtin_bit_cast(half2v, w.w), acc, false);
#else
    const uint wv[4] = {w.x, w.y, w.z, w.w};
    const uint hv[4] = {h.x, h.y, h.z, h.w};
    #pragma unroll
    for (int j = 0; j < 4; ++j) {
        const __half2 wp = __builtin_bit_cast(__half2, wv[j]);
        const __half2 hp = __builtin_bit_cast(__half2, hv[j]);
        acc += __half2float(hp.x) * __half2float(wp.x);
        acc += __half2float(hp.y) * __half2float(wp.y);
    }
#endif
    return acc;
}

// ---------------------------------------------------------------------------
// Pipelined sequential LSTM. Unchanged from round 9 (139 us/dispatch).
// ---------------------------------------------------------------------------
__global__
__attribute__((amdgpu_flat_work_group_size(512, 512)))
__attribute__((amdgpu_waves_per_eu(2, 2)))
void lstm_pipe(int slot,
               const __half* __restrict__ xzAll,
               const uint4* __restrict__ Pr, const uint4* __restrict__ Pn,
               __half* __restrict__ h0, __half* __restrict__ h1,
               float* __restrict__ hsAll, float* __restrict__ csAll)
{
    const int layer = blockIdx.x >> 6;
    const int b     = blockIdx.x & 63;
    const int c     = slot - layer;
    if ((unsigned)c >= (unsigned)NCHUNK) return;
    const int t0 = c * TC;

    const uint4* __restrict__ P = (layer < 2) ? Pr : Pn;
    const __half* __restrict__ xzb =
        xzAll + (size_t)layer * (B_DIM * TC * G_DIM) + (size_t)b * TC * G_DIM;
    const __half* __restrict__ resb =
        (layer == 1) ? (h0 + (size_t)(b * T_DIM + t0) * U_DIM) : nullptr;
    __half* __restrict__ outb =
        (layer == 0) ? (h0 + (size_t)(b * T_DIM + t0) * U_DIM)
      : (layer == 1) ? (h1 + (size_t)(b * T_DIM + t0) * U_DIM) : nullptr;
    float* __restrict__ hstate = hsAll + (size_t)layer * BHID + b * U_DIM;
    float* __restrict__ cstate = csAll + (size_t)layer * BHID + b * U_DIM;

    const int t = threadIdx.x;      // 0..511
    const int n0 = t;               // column A
    const int n1 = t + 512;         // column B

    __shared__ __align__(16) uint hq[U_DIM / 2];   // h as packed f16 (512 B)
    __shared__ float csh[U_DIM];
    __shared__ float zsh[G_DIM];
    __shared__ uint4 wlds[NG_LDS][G_DIM];          // 147 KB

    uint4 wA[NG_REG], wB[NG_REG];
    #pragma unroll
    for (int g = 0; g < NG_REG; ++g) {
        wA[g] = P[(size_t)g * G_DIM + n0];
        wB[g] = P[(size_t)g * G_DIM + n1];
    }
    #pragma unroll
    for (int g = 0; g < NG_REG; ++g) { PIN4(wA[g]); PIN4(wB[g]); }
    #pragma unroll
    for (int g = 0; g < NG_LDS; ++g) {
        wlds[g][n0] = P[(size_t)(NG_REG + g) * G_DIM + n0];
        wlds[g][n1] = P[(size_t)(NG_REG + g) * G_DIM + n1];
    }

    if (t < U_DIM) {
        float hv, cv;
        if (c == 0) { hv = 0.0f; cv = 0.0f; }
        else        { hv = hstate[t]; cv = cstate[t]; }
        csh[t] = cv;
        ((__half*)hq)[t] = __float2half_rn(hv);
    }
    __syncthreads();

    float cur0 = __half2float(xzb[n0]);
    float cur1 = __half2float(xzb[n1]);
    float resv = (resb && t < U_DIM) ? __half2float(resb[t]) : 0.0f;

    for (int tl = 0; tl < TC; ++tl) {
        float acc0 = cur0;
        float acc1 = cur1;

        const int tn = (tl + 1 < TC) ? (tl + 1) : (TC - 1);
        cur0 = __half2float(xzb[(size_t)tn * G_DIM + n0]);
        cur1 = __half2float(xzb[(size_t)tn * G_DIM + n1]);
        const float resn = (resb && t < U_DIM)
                         ? __half2float(resb[(size_t)tn * U_DIM + t]) : 0.0f;

        const uint4* __restrict__ hp = (const uint4*)hq;

        #pragma unroll
        for (int g = 0; g < NG_REG; ++g) {
            const uint4 h4 = hp[g];
            acc0 = mac8(acc0, wA[g], h4);
            acc1 = mac8(acc1, wB[g], h4);
        }
        #pragma unroll
        for (int g = 0; g < NG_LDS; ++g) {
            const uint4 h4 = hp[NG_REG + g];
            acc0 = mac8(acc0, wlds[g][n0], h4);
            acc1 = mac8(acc1, wlds[g][n1], h4);
        }

        zsh[n0] = fsig(acc0);
        zsh[n1] = (t < U_DIM) ? ftanh(acc1) : fsig(acc1);
        __syncthreads();

        if (t < U_DIM) {
            const float iv = zsh[t];
            const float fv = zsh[t + 256];
            const float gv = zsh[t + 512];
            const float ov = zsh[t + 768];
            const float cc = fv * csh[t] + iv * gv;
            const float hh = ov * ftanh(cc);
            csh[t] = cc;
            ((__half*)hq)[t] = __float2half_rn(hh);
            if (outb) outb[(size_t)tl * U_DIM + t] = __float2half_rn(hh + resv);
        }
        resv = resn;
        __syncthreads();
    }

    if (t < U_DIM) {
        hstate[t] = __half2float(((const __half*)hq)[t]);
        cstate[t] = csh[t];
    }
}

// ---------------------------------------------------------------------------
// MFMA input-projection GEMM. Grid (16 Nblk, 64 Mblk, 3 lanes) x 256 threads.
// Lane z, chunk c = slot - z:  out[m,:] = A_z[row(m),:] @ W_z + bias  (f16 out)
// A_z: xh (z=0) / h0 (z=1) / h1 (z=2), all [B, T_DIM, 256] f16.
// Block: 64x64 tile, K=256. Wave w owns col-tile w (16 cols), 4 row-tiles.
// Fragment layouts verified by round 7 (passed): A lane l -> row l&15,
// k = 8*(l>>4)+j; B from group-major pack: P[(4kt + (l>>4))*1024 + col];
// C/D: col = l&15, row = 4*(l>>4)+reg (m89).
// ---------------------------------------------------------------------------
__global__ __launch_bounds__(256)
void gemm3_mfma(int slot,
                const __half* __restrict__ xh,
                const __half* __restrict__ h0, const __half* __restrict__ h1,
                const uint4* __restrict__ PWr, const uint4* __restrict__ PWn,
                const float* __restrict__ br, const float* __restrict__ bn,
                __half* __restrict__ xzAll)
{
    const int z = blockIdx.z;
    const int c = slot - z;
    if ((unsigned)c >= (unsigned)NCHUNK) return;
    const int t0 = c * TC;

    const __half* __restrict__ A = (z == 0) ? xh : ((z == 1) ? h0 : h1);
    const uint4*  __restrict__ PW = (z < 2) ? PWr : PWn;
    const float*  __restrict__ bias = (z < 2) ? br : bn;
    __half* __restrict__ out = xzAll + (size_t)z * (B_DIM * TC * G_DIM);

    const int tid = threadIdx.x;
    const int w = tid >> 6;          // wave -> col-tile
    const int l = tid & 63;

    const int bm = blockIdx.y * 64;  // row base (0..4095)
    const int bn_ = blockIdx.x * 64; // col base (0..1023)
    const int col = bn_ + w * 16 + (l & 15);
    const int krow = l >> 4;         // 0..3: k-subrange selector

    // A row pointers for the 4 row-tiles (lane's row = rt*16 + (l&15))
    const __half* arow[4];
    #pragma unroll
    for (int rt = 0; rt < 4; ++rt) {
        const int m = bm + rt * 16 + (l & 15);
        const int b = m >> 6;              // / TC
        const int tl = m & (TC - 1);
        arow[rt] = A + (size_t)(b * T_DIM + t0 + tl) * U_DIM + krow * 8;
    }

    f32x4 acc[4] = {{0,0,0,0},{0,0,0,0},{0,0,0,0},{0,0,0,0}};

    #pragma unroll
    for (int kt = 0; kt < 8; ++kt) {
        const uint4 bfrag = PW[(size_t)(4 * kt + krow) * G_DIM + col];
        #pragma unroll
        for (int rt = 0; rt < 4; ++rt) {
            const uint4 afrag = *(const uint4*)(arow[rt] + kt * 32);
            acc[rt] = __builtin_amdgcn_mfma_f32_16x16x32_f16(
                __builtin_bit_cast(f16x8, afrag), __builtin_bit_cast(f16x8, bfrag),
                acc[rt], 0, 0, 0);
        }
    }

    const float bv = bias[col];
    #pragma unroll
    for (int rt = 0; rt < 4; ++rt) {
        #pragma unroll
        for (int r = 0; r < 4; ++r) {
            const int m = bm + rt * 16 + 4 * (l >> 4) + r;
            const int b = m >> 6;
            const int tl = m & (TC - 1);
            out[(size_t)(b * TC + tl) * G_DIM + col] = __float2half_rn(acc[rt][r] + bv);
        }
    }
}

// ---------------------------------------------------------------------------
// Final projection, stage A + B (unchanged from round 9).
// ---------------------------------------------------------------------------
__global__ __launch_bounds__(256)
void final_partial(const __half* __restrict__ h1, const float* __restrict__ h2,
                   const float* __restrict__ Wd, float* __restrict__ partials)
{
    const int b = blockIdx.x;
    const int p = blockIdx.y;
    const int tid = threadIdx.x;
    const int JTOT = T_DIM * U_DIM;          // 131072
    const int JPART = JTOT / NPART;          // 16384

    const __half* hb = h1 + (size_t)b * JTOT;
    const float* h2b = h2 + (size_t)b * U_DIM;

    float a0 = 0.f, a1 = 0.f, a2 = 0.f, a3 = 0.f;

    for (int j = p * JPART + tid * 8; j < (p + 1) * JPART; j += 256 * 8) {
        const uint4 hv = *(const uint4*)(hb + j);
        const int m = j & (U_DIM - 1);
        const float4 s0 = *(const float4*)(h2b + m);
        const float4 s1 = *(const float4*)(h2b + m + 4);
        float v[8];
        {
            const __half2 p0 = __builtin_bit_cast(__half2, hv.x);
            const __half2 p1 = __builtin_bit_cast(__half2, hv.y);
            const __half2 p2 = __builtin_bit_cast(__half2, hv.z);
            const __half2 p3 = __builtin_bit_cast(__half2, hv.w);
            v[0] = __half2float(p0.x) + s0.x;
            v[1] = __half2float(p0.y) + s0.y;
            v[2] = __half2float(p1.x) + s0.z;
            v[3] = __half2float(p1.y) + s0.w;
            v[4] = __half2float(p2.x) + s1.x;
            v[5] = __half2float(p2.y) + s1.y;
            v[6] = __half2float(p3.x) + s1.z;
            v[7] = __half2float(p3.y) + s1.w;
        }
        #pragma unroll
        for (int u = 0; u < 8; ++u) {
            const float4 wv = *(const float4*)&Wd[(size_t)(j + u) * 4];
            a0 += v[u] * wv.x;
            a1 += v[u] * wv.y;
            a2 += v[u] * wv.z;
            a3 += v[u] * wv.w;
        }
    }

    __shared__ float red[256][4];
    red[tid][0] = a0; red[tid][1] = a1; red[tid][2] = a2; red[tid][3] = a3;
    __syncthreads();
    for (int s = 128; s > 0; s >>= 1) {
        if (tid < s) {
            #pragma unroll
            for (int o = 0; o < 4; ++o) red[tid][o] += red[tid + s][o];
        }
        __syncthreads();
    }
    if (tid < 4) partials[((size_t)b * NPART + p) * 4 + tid] = red[0][tid];
}

__global__ __launch_bounds__(256)
void final_reduce(const float* __restrict__ partials, const float* __restrict__ bd,
                  float* __restrict__ y)
{
    const int tid = threadIdx.x;
    const int b = tid >> 2;
    const int o = tid & 3;
    float s = bd[o];
    #pragma unroll
    for (int p = 0; p < NPART; ++p)
        s += partials[((size_t)b * NPART + p) * 4 + o];
    y[b * 4 + o] = s;
}

// ---------------------------------------------------------------------------
extern "C" void kernel_launch(void* const* d_in, const int* in_sizes, int n_in,
                              void* d_out, int out_size, void* d_ws, size_t ws_size,
                              hipStream_t stream)
{
    (void)in_sizes; (void)n_in; (void)out_size; (void)ws_size;

    const float* x  = (const float*)d_in[0];
    const float* Wr = (const float*)d_in[1];
    const float* Ur = (const float*)d_in[2];
    const float* br = (const float*)d_in[3];
    const float* Wn = (const float*)d_in[4];
    const float* Un = (const float*)d_in[5];
    const float* bn = (const float*)d_in[6];
    const float* Wd = (const float*)d_in[7];
    const float* bd = (const float*)d_in[8];
    float* y = (float*)d_out;

    // ---- workspace layout (bytes) ----
    char* wp = (char*)d_ws;
    uint4* Pr  = (uint4*)wp;                      wp += (size_t)NG_TOT * G_DIM * 16;  // 512 KB
    uint4* Pn  = (uint4*)wp;                      wp += (size_t)NG_TOT * G_DIM * 16;  // 512 KB
    uint4* PWr = (uint4*)wp;                      wp += (size_t)NG_TOT * G_DIM * 16;  // 512 KB
    uint4* PWn = (uint4*)wp;                      wp += (size_t)NG_TOT * G_DIM * 16;  // 512 KB
    float* hsAll = (float*)wp;                    wp += (size_t)3 * BHID * 4;         // 196 KB
    float* csAll = (float*)wp;                    wp += (size_t)3 * BHID * 4;         // 196 KB
    float* partials = (float*)wp;                 wp += (size_t)B_DIM * NPART * 4 * 4; // 8 KB
    __half* xzAll = (__half*)wp;                  wp += (size_t)3 * B_DIM * TC * G_DIM * 2;  // 25.2 MB
    __half* h0 = (__half*)wp;                     wp += (size_t)B_DIM * T_DIM * U_DIM * 2;   // 16.8 MB
    __half* h1 = (__half*)wp;                     wp += (size_t)B_DIM * T_DIM * U_DIM * 2;   // 16.8 MB
    __half* xh = (__half*)wp;                     wp += (size_t)B_DIM * T_DIM * U_DIM * 2;   // 16.8 MB
    // total ~78 MB

    // ---- one-time packs ----
    pack_w<<<128, 256, 0, stream>>>(Ur, Pr);
    pack_w<<<128, 256, 0, stream>>>(Un, Pn);
    pack_w<<<128, 256, 0, stream>>>(Wr, PWr);
    pack_w<<<128, 256, 0, stream>>>(Wn, PWn);
    pack_x<<<(B_DIM * T_DIM * U_DIM) / (256 * 8), 256, 0, stream>>>(x, xh);

    // ---- software-pipelined layer x chunk wavefront ----
    dim3 ggrid(G_DIM / 64, (B_DIM * TC) / 64, 3);   // (16, 64, 3)
    for (int slot = 0; slot < NSLOT; ++slot) {
        gemm3_mfma<<<ggrid, 256, 0, stream>>>(slot, xh, h0, h1, PWr, PWn,
                                              br, bn, xzAll);
        lstm_pipe<<<3 * B_DIM, 512, 0, stream>>>(slot, xzAll, Pr, Pn,
                                                 h0, h1, hsAll, csAll);
    }

    // ---- final projection ----
    final_partial<<<dim3(B_DIM, NPART), 256, 0, stream>>>(h1, hsAll + 2 * BHID,
                                                          Wd, partials);
    final_reduce<<<1, 256, 0, stream>>>(partials, bd, y);
}

// Round 11
// 1673.006 us; speedup vs baseline: 3.8878x; 1.0163x over previous
//
#include <hip/hip_runtime.h>
#include <hip/hip_fp16.h>
#include <cstddef>
#include <cstdint>

#define U_DIM 256
#define G_DIM 1024          // 4*U
#define T_DIM 512
#define B_DIM 64
#define TC    32            // timesteps per chunk
#define LOG2TC 5
#define NCHUNK (T_DIM / TC) // 16
#define NSLOT  (NCHUNK + 2) // 18 pipeline slots
#define BHID   (B_DIM * U_DIM)
#define NPART  8            // final-proj j-range parts

// Weight residency split for the lstm kernel (proven round-9 structure)
#define NG_TOT 32
#define NG_REG 23
#define NG_LDS 9

typedef _Float16 half2v __attribute__((ext_vector_type(2)));
typedef _Float16 f16x8  __attribute__((ext_vector_type(8)));
typedef float    f32x4  __attribute__((ext_vector_type(4)));

__device__ __forceinline__ float fsig(float x) {
    return 1.0f / (1.0f + __expf(-x));
}
__device__ __forceinline__ float ftanh(float x) {
    return 2.0f * fsig(2.0f * x) - 1.0f;
}

#define PIN4(v) asm("" : "+v"(v.x), "+v"(v.y), "+v"(v.z), "+v"(v.w))

// ---------------------------------------------------------------------------
// Pack U [256,1024] fp32 -> P: [32 groups][1024 cols] of uint4.
// P[g][n] holds f16(U[8g+0..8g+7][n]) packed 2-per-u32.
// (Also the MFMA B-fragment layout: lane reads P[(4kt + (l>>4))*1024 + col].)
// ---------------------------------------------------------------------------
__global__ __launch_bounds__(256)
void pack_w(const float* __restrict__ U, uint4* __restrict__ P)
{
    const int idx = blockIdx.x * 256 + threadIdx.x;   // 0..32767
    const int g = idx >> 10;
    const int n = idx & 1023;
    uint vals[4];
    #pragma unroll
    for (int j = 0; j < 4; ++j) {
        const int k = g * 8 + j * 2;
        const __half a = __float2half_rn(U[(size_t)k * G_DIM + n]);
        const __half b = __float2half_rn(U[(size_t)(k + 1) * G_DIM + n]);
        const unsigned short ua = __builtin_bit_cast(unsigned short, a);
        const unsigned short ub = __builtin_bit_cast(unsigned short, b);
        vals[j] = (uint)ua | ((uint)ub << 16);
    }
    P[idx] = make_uint4(vals[0], vals[1], vals[2], vals[3]);
}

// Pack x f32 -> f16, 8 elems/thread.
__global__ __launch_bounds__(256)
void pack_x(const float* __restrict__ x, __half* __restrict__ xh)
{
    const size_t i = ((size_t)blockIdx.x * 256 + threadIdx.x) * 8;
    const float4 a = *(const float4*)(x + i);
    const float4 b = *(const float4*)(x + i + 4);
    ushort4 o0, o1;
    o0.x = __builtin_bit_cast(unsigned short, __float2half_rn(a.x));
    o0.y = __builtin_bit_cast(unsigned short, __float2half_rn(a.y));
    o0.z = __builtin_bit_cast(unsigned short, __float2half_rn(a.z));
    o0.w = __builtin_bit_cast(unsigned short, __float2half_rn(a.w));
    o1.x = __builtin_bit_cast(unsigned short, __float2half_rn(b.x));
    o1.y = __builtin_bit_cast(unsigned short, __float2half_rn(b.y));
    o1.z = __builtin_bit_cast(unsigned short, __float2half_rn(b.z));
    o1.w = __builtin_bit_cast(unsigned short, __float2half_rn(b.w));
    *(ushort4*)(xh + i) = o0;
    *(ushort4*)(xh + i + 4) = o1;
}

// 8 MACs: acc += sum_j f16(h)[j] * f16(w)[j]   (both packed 2-per-u32)
__device__ __forceinline__ float mac8(float acc, uint4 w, uint4 h)
{
#if __has_builtin(__builtin_amdgcn_fdot2)
    acc = __builtin_amdgcn_fdot2(__builtin_bit_cast(half2v, h.x),
                                 __builtin_bit_cast(half2v, w.x), acc, false);
    acc = __builtin_amdgcn_fdot2(__builtin_bit_cast(half2v, h.y),
                                 __builtin_bit_cast(half2v, w.y), acc, false);
    acc = __builtin_amdgcn_fdot2(__builtin_bit_cast(half2v, h.z),
                                 __builtin_bit_cast(half2v, w.z), acc, false);
    acc = __builtin_amdgcn_fdot2(__builtin_bit_cast(half2v, h.w),
                                 __builtin_bit_cast(half2v, w.w), acc, false);
#else
    const uint wv[4] = {w.x, w.y, w.z, w.w};
    const uint hv[4] = {h.x, h.y, h.z, h.w};
    #pragma unroll
    for (int j = 0; j < 4; ++j) {
        const __half2 wp = __builtin_bit_cast(__half2, wv[j]);
        const __half2 hp = __builtin_bit_cast(__half2, hv[j]);
        acc += __half2float(hp.x) * __half2float(wp.x);
        acc += __half2float(hp.y) * __half2float(wp.y);
    }
#endif
    return acc;
}

// ---------------------------------------------------------------------------
// Pipelined sequential LSTM. Grid = 192 blocks (3 layer-lanes x 64 batch rows).
// Structure unchanged from round 9 (its per-step floor: 2.17 us).
// ---------------------------------------------------------------------------
__global__
__attribute__((amdgpu_flat_work_group_size(512, 512)))
__attribute__((amdgpu_waves_per_eu(2, 2)))
void lstm_pipe(int slot,
               const __half* __restrict__ xzAll,
               const uint4* __restrict__ Pr, const uint4* __restrict__ Pn,
               __half* __restrict__ h0, __half* __restrict__ h1,
               float* __restrict__ hsAll, float* __restrict__ csAll)
{
    const int layer = blockIdx.x >> 6;
    const int b     = blockIdx.x & 63;
    const int c     = slot - layer;
    if ((unsigned)c >= (unsigned)NCHUNK) return;
    const int t0 = c * TC;

    const uint4* __restrict__ P = (layer < 2) ? Pr : Pn;
    const __half* __restrict__ xzb =
        xzAll + (size_t)layer * (B_DIM * TC * G_DIM) + (size_t)b * TC * G_DIM;
    const __half* __restrict__ resb =
        (layer == 1) ? (h0 + (size_t)(b * T_DIM + t0) * U_DIM) : nullptr;
    __half* __restrict__ outb =
        (layer == 0) ? (h0 + (size_t)(b * T_DIM + t0) * U_DIM)
      : (layer == 1) ? (h1 + (size_t)(b * T_DIM + t0) * U_DIM) : nullptr;
    float* __restrict__ hstate = hsAll + (size_t)layer * BHID + b * U_DIM;
    float* __restrict__ cstate = csAll + (size_t)layer * BHID + b * U_DIM;

    const int t = threadIdx.x;      // 0..511
    const int n0 = t;               // column A
    const int n1 = t + 512;         // column B

    __shared__ __align__(16) uint hq[U_DIM / 2];   // h as packed f16 (512 B)
    __shared__ float csh[U_DIM];
    __shared__ float zsh[G_DIM];
    __shared__ uint4 wlds[NG_LDS][G_DIM];          // 147 KB

    uint4 wA[NG_REG], wB[NG_REG];
    #pragma unroll
    for (int g = 0; g < NG_REG; ++g) {
        wA[g] = P[(size_t)g * G_DIM + n0];
        wB[g] = P[(size_t)g * G_DIM + n1];
    }
    #pragma unroll
    for (int g = 0; g < NG_REG; ++g) { PIN4(wA[g]); PIN4(wB[g]); }
    #pragma unroll
    for (int g = 0; g < NG_LDS; ++g) {
        wlds[g][n0] = P[(size_t)(NG_REG + g) * G_DIM + n0];
        wlds[g][n1] = P[(size_t)(NG_REG + g) * G_DIM + n1];
    }

    if (t < U_DIM) {
        float hv, cv;
        if (c == 0) { hv = 0.0f; cv = 0.0f; }
        else        { hv = hstate[t]; cv = cstate[t]; }
        csh[t] = cv;
        ((__half*)hq)[t] = __float2half_rn(hv);
    }
    __syncthreads();

    float cur0 = __half2float(xzb[n0]);
    float cur1 = __half2float(xzb[n1]);
    float resv = (resb && t < U_DIM) ? __half2float(resb[t]) : 0.0f;

    for (int tl = 0; tl < TC; ++tl) {
        float acc0 = cur0;
        float acc1 = cur1;

        const int tn = (tl + 1 < TC) ? (tl + 1) : (TC - 1);
        cur0 = __half2float(xzb[(size_t)tn * G_DIM + n0]);
        cur1 = __half2float(xzb[(size_t)tn * G_DIM + n1]);
        const float resn = (resb && t < U_DIM)
                         ? __half2float(resb[(size_t)tn * U_DIM + t]) : 0.0f;

        const uint4* __restrict__ hp = (const uint4*)hq;

        #pragma unroll
        for (int g = 0; g < NG_REG; ++g) {
            const uint4 h4 = hp[g];
            acc0 = mac8(acc0, wA[g], h4);
            acc1 = mac8(acc1, wB[g], h4);
        }
        #pragma unroll
        for (int g = 0; g < NG_LDS; ++g) {
            const uint4 h4 = hp[NG_REG + g];
            acc0 = mac8(acc0, wlds[g][n0], h4);
            acc1 = mac8(acc1, wlds[g][n1], h4);
        }

        zsh[n0] = fsig(acc0);
        zsh[n1] = (t < U_DIM) ? ftanh(acc1) : fsig(acc1);
        __syncthreads();

        if (t < U_DIM) {
            const float iv = zsh[t];
            const float fv = zsh[t + 256];
            const float gv = zsh[t + 512];
            const float ov = zsh[t + 768];
            const float cc = fv * csh[t] + iv * gv;
            const float hh = ov * ftanh(cc);
            csh[t] = cc;
            ((__half*)hq)[t] = __float2half_rn(hh);
            if (outb) outb[(size_t)tl * U_DIM + t] = __float2half_rn(hh + resv);
        }
        resv = resn;
        __syncthreads();
    }

    if (t < U_DIM) {
        hstate[t] = __half2float(((const __half*)hq)[t]);
        cstate[t] = csh[t];
    }
}

// ---------------------------------------------------------------------------
// MFMA input-projection GEMM. Grid (16 Nblk, (B*TC)/64 Mblk, 3 lanes) x 256 thr.
// Epilogue now stages the 64x64 f16 C-tile in LDS (stride 68 halves,
// conflict-free) and writes coalesced 16B ushort8 rows.
// ---------------------------------------------------------------------------
__global__ __launch_bounds__(256)
void gemm3_mfma(int slot,
                const __half* __restrict__ xh,
                const __half* __restrict__ h0, const __half* __restrict__ h1,
                const uint4* __restrict__ PWr, const uint4* __restrict__ PWn,
                const float* __restrict__ br, const float* __restrict__ bn,
                __half* __restrict__ xzAll)
{
    const int z = blockIdx.z;
    const int c = slot - z;
    if ((unsigned)c >= (unsigned)NCHUNK) return;
    const int t0 = c * TC;

    const __half* __restrict__ A = (z == 0) ? xh : ((z == 1) ? h0 : h1);
    const uint4*  __restrict__ PW = (z < 2) ? PWr : PWn;
    const float*  __restrict__ bias = (z < 2) ? br : bn;
    __half* __restrict__ out = xzAll + (size_t)z * (B_DIM * TC * G_DIM);

    const int tid = threadIdx.x;
    const int w = tid >> 6;          // wave -> col-tile
    const int l = tid & 63;

    const int bm = blockIdx.y * 64;  // row base within chunk (0..B*TC-1)
    const int bn_ = blockIdx.x * 64; // col base (0..1023)
    const int col = bn_ + w * 16 + (l & 15);
    const int krow = l >> 4;         // 0..3: k-subrange selector

    __shared__ __half ctile[64][68];  // 8.5 KB, padded: conflict-free epilogue

    // A row pointers for the 4 row-tiles (lane's row = rt*16 + (l&15))
    const __half* arow[4];
    #pragma unroll
    for (int rt = 0; rt < 4; ++rt) {
        const int m = bm + rt * 16 + (l & 15);
        const int b = m >> LOG2TC;
        const int tl = m & (TC - 1);
        arow[rt] = A + (size_t)(b * T_DIM + t0 + tl) * U_DIM + krow * 8;
    }

    f32x4 acc[4] = {{0,0,0,0},{0,0,0,0},{0,0,0,0},{0,0,0,0}};

    #pragma unroll
    for (int kt = 0; kt < 8; ++kt) {
        const uint4 bfrag = PW[(size_t)(4 * kt + krow) * G_DIM + col];
        #pragma unroll
        for (int rt = 0; rt < 4; ++rt) {
            const uint4 afrag = *(const uint4*)(arow[rt] + kt * 32);
            acc[rt] = __builtin_amdgcn_mfma_f32_16x16x32_f16(
                __builtin_bit_cast(f16x8, afrag), __builtin_bit_cast(f16x8, bfrag),
                acc[rt], 0, 0, 0);
        }
    }

    // ---- epilogue: bias, stage to LDS, coalesced write ----
    const float bv = bias[col];
    const int ccol = w * 16 + (l & 15);
    #pragma unroll
    for (int rt = 0; rt < 4; ++rt) {
        #pragma unroll
        for (int r = 0; r < 4; ++r) {
            const int crow = rt * 16 + 4 * (l >> 4) + r;
            ctile[crow][ccol] = __float2half_rn(acc[rt][r] + bv);
        }
    }
    __syncthreads();

    {
        const int row = tid >> 2;          // 0..63
        const int quad = (tid & 3) * 16;   // 0,16,32,48
        const int m = bm + row;
        const int b = m >> LOG2TC;
        const int tl = m & (TC - 1);
        __half* dst = out + (size_t)(b * TC + tl) * G_DIM + bn_ + quad;
        const uint4 v0 = *(const uint4*)&ctile[row][quad];
        const uint4 v1 = *(const uint4*)&ctile[row][quad + 8];
        *(uint4*)dst = v0;
        *(uint4*)(dst + 8) = v1;
    }
}

// ---------------------------------------------------------------------------
// Final projection, stage A + B (unchanged).
// ---------------------------------------------------------------------------
__global__ __launch_bounds__(256)
void final_partial(const __half* __restrict__ h1, const float* __restrict__ h2,
                   const float* __restrict__ Wd, float* __restrict__ partials)
{
    const int b = blockIdx.x;
    const int p = blockIdx.y;
    const int tid = threadIdx.x;
    const int JTOT = T_DIM * U_DIM;          // 131072
    const int JPART = JTOT / NPART;          // 16384

    const __half* hb = h1 + (size_t)b * JTOT;
    const float* h2b = h2 + (size_t)b * U_DIM;

    float a0 = 0.f, a1 = 0.f, a2 = 0.f, a3 = 0.f;

    for (int j = p * JPART + tid * 8; j < (p + 1) * JPART; j += 256 * 8) {
        const uint4 hv = *(const uint4*)(hb + j);
        const int m = j & (U_DIM - 1);
        const float4 s0 = *(const float4*)(h2b + m);
        const float4 s1 = *(const float4*)(h2b + m + 4);
        float v[8];
        {
            const __half2 p0 = __builtin_bit_cast(__half2, hv.x);
            const __half2 p1 = __builtin_bit_cast(__half2, hv.y);
            const __half2 p2 = __builtin_bit_cast(__half2, hv.z);
            const __half2 p3 = __builtin_bit_cast(__half2, hv.w);
            v[0] = __half2float(p0.x) + s0.x;
            v[1] = __half2float(p0.y) + s0.y;
            v[2] = __half2float(p1.x) + s0.z;
            v[3] = __half2float(p1.y) + s0.w;
            v[4] = __half2float(p2.x) + s1.x;
            v[5] = __half2float(p2.y) + s1.y;
            v[6] = __half2float(p3.x) + s1.z;
            v[7] = __half2float(p3.y) + s1.w;
        }
        #pragma unroll
        for (int u = 0; u < 8; ++u) {
            const float4 wv = *(const float4*)&Wd[(size_t)(j + u) * 4];
            a0 += v[u] * wv.x;
            a1 += v[u] * wv.y;
            a2 += v[u] * wv.z;
            a3 += v[u] * wv.w;
        }
    }

    __shared__ float red[256][4];
    red[tid][0] = a0; red[tid][1] = a1; red[tid][2] = a2; red[tid][3] = a3;
    __syncthreads();
    for (int s = 128; s > 0; s >>= 1) {
        if (tid < s) {
            #pragma unroll
            for (int o = 0; o < 4; ++o) red[tid][o] += red[tid + s][o];
        }
        __syncthreads();
    }
    if (tid < 4) partials[((size_t)b * NPART + p) * 4 + tid] = red[0][tid];
}

__global__ __launch_bounds__(256)
void final_reduce(const float* __restrict__ partials, const float* __restrict__ bd,
                  float* __restrict__ y)
{
    const int tid = threadIdx.x;
    const int b = tid >> 2;
    const int o = tid & 3;
    float s = bd[o];
    #pragma unroll
    for (int p = 0; p < NPART; ++p)
        s += partials[((size_t)b * NPART + p) * 4 + o];
    y[b * 4 + o] = s;
}

// ---------------------------------------------------------------------------
extern "C" void kernel_launch(void* const* d_in, const int* in_sizes, int n_in,
                              void* d_out, int out_size, void* d_ws, size_t ws_size,
                              hipStream_t stream)
{
    (void)in_sizes; (void)n_in; (void)out_size; (void)ws_size;

    const float* x  = (const float*)d_in[0];
    const float* Wr = (const float*)d_in[1];
    const float* Ur = (const float*)d_in[2];
    const float* br = (const float*)d_in[3];
    const float* Wn = (const float*)d_in[4];
    const float* Un = (const float*)d_in[5];
    const float* bn = (const float*)d_in[6];
    const float* Wd = (const float*)d_in[7];
    const float* bd = (const float*)d_in[8];
    float* y = (float*)d_out;

    // ---- workspace layout (bytes) ----
    char* wp = (char*)d_ws;
    uint4* Pr  = (uint4*)wp;                      wp += (size_t)NG_TOT * G_DIM * 16;  // 512 KB
    uint4* Pn  = (uint4*)wp;                      wp += (size_t)NG_TOT * G_DIM * 16;  // 512 KB
    uint4* PWr = (uint4*)wp;                      wp += (size_t)NG_TOT * G_DIM * 16;  // 512 KB
    uint4* PWn = (uint4*)wp;                      wp += (size_t)NG_TOT * G_DIM * 16;  // 512 KB
    float* hsAll = (float*)wp;                    wp += (size_t)3 * BHID * 4;         // 196 KB
    float* csAll = (float*)wp;                    wp += (size_t)3 * BHID * 4;         // 196 KB
    float* partials = (float*)wp;                 wp += (size_t)B_DIM * NPART * 4 * 4; // 8 KB
    __half* xzAll = (__half*)wp;                  wp += (size_t)3 * B_DIM * TC * G_DIM * 2;  // 12.6 MB
    __half* h0 = (__half*)wp;                     wp += (size_t)B_DIM * T_DIM * U_DIM * 2;   // 16.8 MB
    __half* h1 = (__half*)wp;                     wp += (size_t)B_DIM * T_DIM * U_DIM * 2;   // 16.8 MB
    __half* xh = (__half*)wp;                     wp += (size_t)B_DIM * T_DIM * U_DIM * 2;   // 16.8 MB
    // total ~65 MB

    // ---- one-time packs ----
    pack_w<<<128, 256, 0, stream>>>(Ur, Pr);
    pack_w<<<128, 256, 0, stream>>>(Un, Pn);
    pack_w<<<128, 256, 0, stream>>>(Wr, PWr);
    pack_w<<<128, 256, 0, stream>>>(Wn, PWn);
    pack_x<<<(B_DIM * T_DIM * U_DIM) / (256 * 8), 256, 0, stream>>>(x, xh);

    // ---- software-pipelined layer x chunk wavefront ----
    dim3 ggrid(G_DIM / 64, (B_DIM * TC) / 64, 3);   // (16, 32, 3)
    for (int slot = 0; slot < NSLOT; ++slot) {
        gemm3_mfma<<<ggrid, 256, 0, stream>>>(slot, xh, h0, h1, PWr, PWn,
                                              br, bn, xzAll);
        lstm_pipe<<<3 * B_DIM, 512, 0, stream>>>(slot, xzAll, Pr, Pn,
                                                 h0, h1, hsAll, csAll);
    }

    // ---- final projection ----
    final_partial<<<dim3(B_DIM, NPART), 256, 0, stream>>>(h1, hsAll + 2 * BHID,
                                                          Wd, partials);
    final_reduce<<<1, 256, 0, stream>>>(partials, bd, y);
}